// Round 1
// baseline (1402.117 us; speedup 1.0000x reference)
//
#include <hip/hip_runtime.h>

#define T_STEPS 256
#define BATCH   2048
#define HID     128

typedef short short8  __attribute__((ext_vector_type(8)));
typedef float float4v __attribute__((ext_vector_type(4)));

__device__ __forceinline__ unsigned short f2bf(float f) {
    unsigned int u = __builtin_bit_cast(unsigned int, f);
    u += 0x7fffu + ((u >> 16) & 1u);          // round-to-nearest-even
    return (unsigned short)(u >> 16);
}
__device__ __forceinline__ float bf2f(unsigned short b) {
    unsigned int u = ((unsigned int)b) << 16;
    return __builtin_bit_cast(float, u);
}
__device__ __forceinline__ float sigf(float x)      { return 1.0f / (1.0f + __expf(-x)); }
__device__ __forceinline__ float tanh_fast(float x) { return 2.0f / (1.0f + __expf(-2.0f * x)) - 1.0f; }

// LDS address for the activation tile a_lds[16 rows][256 bf16 cols = 512 B],
// XOR-swizzled (G4) so stride-512B per-row b128 reads are ~2-way conflict free.
__device__ __forceinline__ int lpos(int row, int byteoff) {
    return (row * 512 + byteoff) ^ ((row & 7) << 4);
}

__device__ __forceinline__ short8 load_w8(const float* __restrict__ p) {
    float4v a = *reinterpret_cast<const float4v*>(p);
    float4v b = *reinterpret_cast<const float4v*>(p + 4);
    short8 r;
    r[0] = (short)f2bf(a[0]); r[1] = (short)f2bf(a[1]);
    r[2] = (short)f2bf(a[2]); r[3] = (short)f2bf(a[3]);
    r[4] = (short)f2bf(b[0]); r[5] = (short)f2bf(b[1]);
    r[6] = (short)f2bf(b[2]); r[7] = (short)f2bf(b[3]);
    return r;
}

// One LSTM layer, persistent over all T per block. Block = 512 thr (8 waves),
// 16 batch rows/block. Wave w owns gate columns [16w,16w+16) of each gate
// (n-tiles {w, w+8, w+16, w+24}) -> c/h update is lane-local, weights live in
// registers (no per-step LDS weight traffic).
template<bool IS_L0, bool WRITE_H, bool FINAL>
__global__ __launch_bounds__(512)
void lstm_layer(const float* __restrict__ x0,
                const float* __restrict__ Wih,
                const float* __restrict__ Whh,
                const float* __restrict__ bih,
                const float* __restrict__ bhh,
                unsigned short* __restrict__ hbuf,   // [T][B][H] bf16, in-place across layers
                const float* __restrict__ Wfc,
                const float* __restrict__ bfc,
                float* __restrict__ out)
{
    constexpr int KS_TOT = IS_L0 ? 5 : 8;           // K = 128 (h) + 128 or 32-padded (x)
    __shared__ __attribute__((aligned(16))) unsigned char a_lds[16 * 512];

    const int tid   = threadIdx.x;
    const int lane  = tid & 63;
    const int wv    = tid >> 6;                     // wave 0..7
    const int b0    = blockIdx.x * 16;

    const int t16   = lane & 15;                    // A row (m) / B col (n) low bits
    const int kgrp8 = (lane >> 4) * 8;              // k base within a 32-slice
    const int jcol  = 16 * wv + t16;                // owned h column
    const int m0    = (lane >> 4) * 4;              // acc rows base (C/D layout)

    // zero LDS (h(-1)=0 and layer-0 K-pad cols stay zero forever)
    {
        short8 z = {0,0,0,0,0,0,0,0};
        *reinterpret_cast<short8*>(&a_lds[tid * 16]) = z;
    }

    // ---- weights -> registers (bf16 fragments), bias -> registers ----
    short8 wf[4][KS_TOT];
    float  bias[4];
    #pragma unroll
    for (int q = 0; q < 4; ++q) {                   // q: gate i,f,g,o
        const int n = 128 * q + jcol;               // row of Wih/Whh
        bias[q] = bih[n] + bhh[n];
        #pragma unroll
        for (int ks = 0; ks < 4; ++ks)
            wf[q][ks] = load_w8(Whh + n * 128 + ks * 32 + kgrp8);
        if (IS_L0) {
            if (kgrp8 < 24) wf[q][4] = load_w8(Wih + n * 24 + kgrp8);
            else            { short8 z = {0,0,0,0,0,0,0,0}; wf[q][4] = z; }
        } else {
            #pragma unroll
            for (int ks = 4; ks < 8; ++ks)
                wf[q][ks] = load_w8(Wih + n * 128 + (ks - 4) * 32 + kgrp8);
        }
    }

    // staging thread mapping
    const int m16 = tid >> 4, c16 = tid & 15;       // tid<256: row, 16B chunk
    const int m12 = tid / 12, p12 = tid % 12;       // tid<192: row, float2 pair (L0)

    float creg[4] = {0.f, 0.f, 0.f, 0.f};

    // prefetch x(0)
    short8 xp; float xfa = 0.f, xfb = 0.f;
    if (!IS_L0) {
        if (tid < 256)
            xp = *reinterpret_cast<const short8*>(&hbuf[((size_t)0 * BATCH + b0 + m16) * HID + c16 * 8]);
    } else {
        if (tid < 192) {
            const float2 v = *reinterpret_cast<const float2*>(
                &x0[(size_t)(b0 + m12) * (T_STEPS * 24) + 0 * 24 + 2 * p12]);
            xfa = v.x; xfb = v.y;
        }
    }
    __syncthreads();                                // zeros visible

    // stage x(0) into a_lds cols 128..255
    if (!IS_L0) {
        if (tid < 256)
            *reinterpret_cast<short8*>(&a_lds[lpos(m16, 256 + c16 * 16)]) = xp;
    } else {
        if (tid < 192) {
            unsigned int pv = (unsigned int)f2bf(xfa) | ((unsigned int)f2bf(xfb) << 16);
            *reinterpret_cast<unsigned int*>(&a_lds[lpos(m12, 256 + 4 * p12)]) = pv;
        }
    }
    __syncthreads();

    for (int t = 0; t < T_STEPS; ++t) {
        // overlap with MFMA: write h(t-1) to global (coalesced 16B/lane)
        if (WRITE_H) {
            if (t > 0 && tid < 256) {
                short8 hv = *reinterpret_cast<const short8*>(&a_lds[lpos(m16, c16 * 16)]);
                *reinterpret_cast<short8*>(
                    &hbuf[((size_t)(t - 1) * BATCH + b0 + m16) * HID + c16 * 8]) = hv;
            }
        }
        // prefetch x(t+1) into registers (latency hides under MFMA)
        if (t + 1 < T_STEPS) {
            if (!IS_L0) {
                if (tid < 256)
                    xp = *reinterpret_cast<const short8*>(
                        &hbuf[((size_t)(t + 1) * BATCH + b0 + m16) * HID + c16 * 8]);
            } else {
                if (tid < 192) {
                    const float2 v = *reinterpret_cast<const float2*>(
                        &x0[(size_t)(b0 + m12) * (T_STEPS * 24) + (t + 1) * 24 + 2 * p12]);
                    xfa = v.x; xfb = v.y;
                }
            }
        }

        // gates = [h | x] @ [Whh | Wih]^T + (bih+bhh)
        float4v acc0 = {bias[0], bias[0], bias[0], bias[0]};
        float4v acc1 = {bias[1], bias[1], bias[1], bias[1]};
        float4v acc2 = {bias[2], bias[2], bias[2], bias[2]};
        float4v acc3 = {bias[3], bias[3], bias[3], bias[3]};
        #pragma unroll
        for (int ks = 0; ks < KS_TOT; ++ks) {
            const int boff = (ks < 4) ? (ks * 64 + kgrp8 * 2)
                                      : (256 + (ks - 4) * 64 + kgrp8 * 2);
            short8 av = *reinterpret_cast<const short8*>(&a_lds[lpos(t16, boff)]);
            acc0 = __builtin_amdgcn_mfma_f32_16x16x32_bf16(av, wf[0][ks], acc0, 0, 0, 0);
            acc1 = __builtin_amdgcn_mfma_f32_16x16x32_bf16(av, wf[1][ks], acc1, 0, 0, 0);
            acc2 = __builtin_amdgcn_mfma_f32_16x16x32_bf16(av, wf[2][ks], acc2, 0, 0, 0);
            acc3 = __builtin_amdgcn_mfma_f32_16x16x32_bf16(av, wf[3][ks], acc3, 0, 0, 0);
        }

        // lane-local cell update: rows m0..m0+3, column jcol
        unsigned short hbits[4];
        #pragma unroll
        for (int r = 0; r < 4; ++r) {
            const float iv = sigf(acc0[r]);
            const float fv = sigf(acc1[r]);
            const float gv = tanh_fast(acc2[r]);
            const float ov = sigf(acc3[r]);
            const float cv = fv * creg[r] + iv * gv;
            creg[r] = cv;
            hbits[r] = f2bf(ov * tanh_fast(cv));
        }
        __syncthreads();                            // B1: all a_lds reads done

        // write h(t) into a_lds cols 0..127
        #pragma unroll
        for (int r = 0; r < 4; ++r)
            *reinterpret_cast<unsigned short*>(&a_lds[lpos(m0 + r, 2 * jcol)]) = hbits[r];

        // stage x(t+1)
        if (t + 1 < T_STEPS) {
            if (!IS_L0) {
                if (tid < 256)
                    *reinterpret_cast<short8*>(&a_lds[lpos(m16, 256 + c16 * 16)]) = xp;
            } else {
                if (tid < 192) {
                    unsigned int pv = (unsigned int)f2bf(xfa) | ((unsigned int)f2bf(xfb) << 16);
                    *reinterpret_cast<unsigned int*>(&a_lds[lpos(m12, 256 + 4 * p12)]) = pv;
                }
            }
        }
        __syncthreads();                            // B2: h(t)/x(t+1) visible
    }

    // flush h(T-1)
    if (WRITE_H && tid < 256) {
        short8 hv = *reinterpret_cast<const short8*>(&a_lds[lpos(m16, c16 * 16)]);
        *reinterpret_cast<short8*>(
            &hbuf[((size_t)(T_STEPS - 1) * BATCH + b0 + m16) * HID + c16 * 8]) = hv;
    }
    // fused final FC: out[b] = h_255[b] . Wfc + bfc
    if (FINAL && tid < 16) {
        float s = bfc[0];
        #pragma unroll 8
        for (int j = 0; j < HID; ++j)
            s += bf2f(*reinterpret_cast<const unsigned short*>(&a_lds[lpos(tid, 2 * j)])) * Wfc[j];
        out[b0 + tid] = s;
    }
}

extern "C" void kernel_launch(void* const* d_in, const int* in_sizes, int n_in,
                              void* d_out, int out_size, void* d_ws, size_t ws_size,
                              hipStream_t stream) {
    (void)in_sizes; (void)n_in; (void)out_size; (void)ws_size;
    const float* x    = (const float*)d_in[0];
    const float* Wih0 = (const float*)d_in[1];
    const float* Whh0 = (const float*)d_in[2];
    const float* bih0 = (const float*)d_in[3];
    const float* bhh0 = (const float*)d_in[4];
    const float* Wih1 = (const float*)d_in[5];
    const float* Whh1 = (const float*)d_in[6];
    const float* bih1 = (const float*)d_in[7];
    const float* bhh1 = (const float*)d_in[8];
    const float* Wih2 = (const float*)d_in[9];
    const float* Whh2 = (const float*)d_in[10];
    const float* bih2 = (const float*)d_in[11];
    const float* bhh2 = (const float*)d_in[12];
    const float* Wfc  = (const float*)d_in[13];
    const float* bfc  = (const float*)d_in[14];
    float* out = (float*)d_out;
    unsigned short* hbuf = (unsigned short*)d_ws;   // [256][2048][128] bf16 = 134 MB

    dim3 grid(BATCH / 16), block(512);
    lstm_layer<true,  true,  false><<<grid, block, 0, stream>>>(x,       Wih0, Whh0, bih0, bhh0, hbuf, nullptr, nullptr, nullptr);
    lstm_layer<false, true,  false><<<grid, block, 0, stream>>>(nullptr, Wih1, Whh1, bih1, bhh1, hbuf, nullptr, nullptr, nullptr);
    lstm_layer<false, false, true ><<<grid, block, 0, stream>>>(nullptr, Wih2, Whh2, bih2, bhh2, hbuf, Wfc,     bfc,     out);
}

// Round 2
// 1389.954 us; speedup vs baseline: 1.0088x; 1.0088x over previous
//
#include <hip/hip_runtime.h>

#define T_STEPS 256
#define BATCH   2048
#define HID     128

typedef short short8  __attribute__((ext_vector_type(8)));
typedef short short4v __attribute__((ext_vector_type(4)));
typedef float float4v __attribute__((ext_vector_type(4)));

__device__ __forceinline__ unsigned short f2bf(float f) {
    unsigned int u = __builtin_bit_cast(unsigned int, f);
    u += 0x7fffu + ((u >> 16) & 1u);          // round-to-nearest-even
    return (unsigned short)(u >> 16);
}
__device__ __forceinline__ float bf2f(unsigned short b) {
    unsigned int u = ((unsigned int)b) << 16;
    return __builtin_bit_cast(float, u);
}
__device__ __forceinline__ float sigf(float x)      { return 1.0f / (1.0f + __expf(-x)); }
__device__ __forceinline__ float tanh_fast(float x) { return 2.0f / (1.0f + __expf(-2.0f * x)) - 1.0f; }

// LDS address within one 8 KB buffer: a[16 rows][512 B], XOR-swizzled (G4).
__device__ __forceinline__ int lpos(int row, int byteoff) {
    return (row * 512 + byteoff) ^ ((row & 7) << 4);
}

__device__ __forceinline__ short8 load_w8(const float* __restrict__ p) {
    float4v a = *reinterpret_cast<const float4v*>(p);
    float4v b = *reinterpret_cast<const float4v*>(p + 4);
    short8 r;
    r[0] = (short)f2bf(a[0]); r[1] = (short)f2bf(a[1]);
    r[2] = (short)f2bf(a[2]); r[3] = (short)f2bf(a[3]);
    r[4] = (short)f2bf(b[0]); r[5] = (short)f2bf(b[1]);
    r[6] = (short)f2bf(b[2]); r[7] = (short)f2bf(b[3]);
    return r;
}

// One LSTM layer. Block = 512 thr (8 waves), 16 batch rows, persistent over T.
// Ping-pong LDS (1 barrier/step), depth-2 x prefetch, weights in registers.
template<bool IS_L0, bool WRITE_H, bool FINAL>
__global__ __launch_bounds__(512, 2)
void lstm_layer(const float* __restrict__ x0,
                const float* __restrict__ Wih,
                const float* __restrict__ Whh,
                const float* __restrict__ bih,
                const float* __restrict__ bhh,
                unsigned short* __restrict__ hbuf,   // [T][B][H] bf16
                const float* __restrict__ Wfc,
                const float* __restrict__ bfc,
                float* __restrict__ out)
{
    constexpr int KS_TOT = IS_L0 ? 5 : 8;
    __shared__ __attribute__((aligned(16))) unsigned char a_lds[2 * 16 * 512];

    const int tid   = threadIdx.x;
    const int lane  = tid & 63;
    const int wv    = tid >> 6;
    const int b0    = blockIdx.x * 16;

    const int t16   = lane & 15;
    const int kgrp8 = (lane >> 4) * 8;
    const int jcol  = 16 * wv + t16;
    const int m0    = (lane >> 4) * 4;

    // precomputed LDS offsets (within one buffer; add rb/wb = 0 or 8192)
    int aoff[KS_TOT];
    #pragma unroll
    for (int ks = 0; ks < KS_TOT; ++ks) {
        const int boff = (ks < 4) ? (ks * 64 + kgrp8 * 2)
                                  : (256 + (ks - 4) * 64 + kgrp8 * 2);
        aoff[ks] = lpos(t16, boff);
    }
    int hwoff[4];
    #pragma unroll
    for (int r = 0; r < 4; ++r) hwoff[r] = lpos(m0 + r, 2 * jcol);

    // staging map: 512 threads x 8 B cover 16 rows x 256 B
    const int srow  = tid >> 5, so8 = tid & 31;
    const int hroff = lpos(srow, so8 * 8);            // h region read (for global write)
    const int sloff = lpos(srow, 256 + so8 * 8);      // x region write
    const size_t sgoff = (size_t)(b0 + srow) * HID + so8 * 4;  // shorts
    // L0 x staging: 384 threads x 1 float cover 16 rows x 24
    const int  xrow   = tid / 24, xe = tid % 24;
    const bool xvalid = tid < 384;
    const int  l0_loff = xvalid ? lpos(xrow, 256 + 2 * xe) : 0;
    const size_t l0_goff = xvalid ? ((size_t)(b0 + xrow) * (T_STEPS * 24) + xe) : 0;

    // ---- weights -> registers ----
    short8 wf[4][KS_TOT];
    float  bias[4];
    #pragma unroll
    for (int q = 0; q < 4; ++q) {
        const int n = 128 * q + jcol;
        bias[q] = bih[n] + bhh[n];
        #pragma unroll
        for (int ks = 0; ks < 4; ++ks)
            wf[q][ks] = load_w8(Whh + n * 128 + ks * 32 + kgrp8);
        if (IS_L0) {
            if (kgrp8 < 24) wf[q][4] = load_w8(Wih + n * 24 + kgrp8);
            else            { short8 z = {0,0,0,0,0,0,0,0}; wf[q][4] = z; }
        } else {
            #pragma unroll
            for (int ks = 4; ks < 8; ++ks)
                wf[q][ks] = load_w8(Wih + n * 128 + (ks - 4) * 32 + kgrp8);
        }
    }

    // zero both LDS buffers (h(-1)=0; pad columns stay 0)
    {
        short8 z = {0,0,0,0,0,0,0,0};
        *reinterpret_cast<short8*>(&a_lds[tid * 16])        = z;
        *reinterpret_cast<short8*>(&a_lds[8192 + tid * 16]) = z;
    }
    __syncthreads();

    // prologue: stage x(0) into buf0; hold x(1) in regs
    short4v xh = {0, 0, 0, 0};
    float   xf = 0.f;
    if (!IS_L0) {
        short4v v0 = *reinterpret_cast<const short4v*>(&hbuf[sgoff]);  // t=0
        *reinterpret_cast<short4v*>(&a_lds[sloff]) = v0;
        xh = *reinterpret_cast<const short4v*>(&hbuf[(size_t)BATCH * HID + sgoff]); // t=1
    } else if (xvalid) {
        float v0 = x0[l0_goff];
        *reinterpret_cast<unsigned short*>(&a_lds[l0_loff]) = f2bf(v0);
        xf = x0[l0_goff + 24];                                          // t=1
    }
    __syncthreads();

    float creg[4] = {0.f, 0.f, 0.f, 0.f};

    auto step = [&](int t, int rb, int wb) {
        // A: global write of h(t-1) (in read buffer), overlapped with compute
        if (WRITE_H && t > 0) {
            short4v hv = *reinterpret_cast<const short4v*>(&a_lds[rb + hroff]);
            *reinterpret_cast<short4v*>(
                &hbuf[(size_t)(t - 1) * (BATCH * HID) + sgoff]) = hv;
        }
        // B: stage x(t+1) from regs loaded a full step ago (no vmcnt stall)
        if (t + 1 < T_STEPS) {
            if (!IS_L0)
                *reinterpret_cast<short4v*>(&a_lds[wb + sloff]) = xh;
            else if (xvalid)
                *reinterpret_cast<unsigned short*>(&a_lds[wb + l0_loff]) = f2bf(xf);
        }
        // C: issue load of x(t+2)
        if (t + 2 < T_STEPS) {
            if (!IS_L0)
                xh = *reinterpret_cast<const short4v*>(
                    &hbuf[(size_t)(t + 2) * (BATCH * HID) + sgoff]);
            else if (xvalid)
                xf = x0[l0_goff + (size_t)(t + 2) * 24];
        }
        // D: MFMA, split even/odd-ks chains (8 independent chains)
        float4v aA[4], aB[4];
        #pragma unroll
        for (int q = 0; q < 4; ++q) {
            aA[q] = float4v{bias[q], bias[q], bias[q], bias[q]};
            aB[q] = float4v{0.f, 0.f, 0.f, 0.f};
        }
        #pragma unroll
        for (int ks = 0; ks < KS_TOT; ++ks) {
            short8 av = *reinterpret_cast<const short8*>(&a_lds[rb + aoff[ks]]);
            if (ks & 1) {
                #pragma unroll
                for (int q = 0; q < 4; ++q)
                    aB[q] = __builtin_amdgcn_mfma_f32_16x16x32_bf16(av, wf[q][ks], aB[q], 0, 0, 0);
            } else {
                #pragma unroll
                for (int q = 0; q < 4; ++q)
                    aA[q] = __builtin_amdgcn_mfma_f32_16x16x32_bf16(av, wf[q][ks], aA[q], 0, 0, 0);
            }
        }
        // E/F: lane-local cell update, write h(t) into write buffer
        #pragma unroll
        for (int r = 0; r < 4; ++r) {
            const float iv = sigf(aA[0][r] + aB[0][r]);
            const float fv = sigf(aA[1][r] + aB[1][r]);
            const float gv = tanh_fast(aA[2][r] + aB[2][r]);
            const float ov = sigf(aA[3][r] + aB[3][r]);
            const float cv = fv * creg[r] + iv * gv;
            creg[r] = cv;
            *reinterpret_cast<unsigned short*>(&a_lds[wb + hwoff[r]]) =
                f2bf(ov * tanh_fast(cv));
        }
        // G: single barrier per step
        __syncthreads();
    };

    for (int th = 0; th < T_STEPS / 2; ++th) {
        step(2 * th,     0,    8192);
        step(2 * th + 1, 8192, 0);
    }
    // h(T-1) sits in buf0 (255 odd: wrote to buffer 0); loop-end barrier done.
    if (WRITE_H) {
        short4v hv = *reinterpret_cast<const short4v*>(&a_lds[hroff]);
        *reinterpret_cast<short4v*>(
            &hbuf[(size_t)(T_STEPS - 1) * (BATCH * HID) + sgoff]) = hv;
    }
    // fused final FC (wave-parallel): out[b] = h_255[b] . Wfc + bfc
    if (FINAL && tid < 256) {
        const int r = tid >> 4, seg = tid & 15;
        float s = 0.f;
        #pragma unroll
        for (int k = 0; k < 8; ++k) {
            const int j = seg * 8 + k;
            s += bf2f(*reinterpret_cast<const unsigned short*>(&a_lds[lpos(r, 2 * j)]))
                 * Wfc[j];
        }
        #pragma unroll
        for (int off = 8; off >= 1; off >>= 1) s += __shfl_xor(s, off);
        if (seg == 0) out[b0 + r] = s + bfc[0];
    }
}

extern "C" void kernel_launch(void* const* d_in, const int* in_sizes, int n_in,
                              void* d_out, int out_size, void* d_ws, size_t ws_size,
                              hipStream_t stream) {
    (void)in_sizes; (void)n_in; (void)out_size; (void)ws_size;
    const float* x    = (const float*)d_in[0];
    const float* Wih0 = (const float*)d_in[1];
    const float* Whh0 = (const float*)d_in[2];
    const float* bih0 = (const float*)d_in[3];
    const float* bhh0 = (const float*)d_in[4];
    const float* Wih1 = (const float*)d_in[5];
    const float* Whh1 = (const float*)d_in[6];
    const float* bih1 = (const float*)d_in[7];
    const float* bhh1 = (const float*)d_in[8];
    const float* Wih2 = (const float*)d_in[9];
    const float* Whh2 = (const float*)d_in[10];
    const float* bih2 = (const float*)d_in[11];
    const float* bhh2 = (const float*)d_in[12];
    const float* Wfc  = (const float*)d_in[13];
    const float* bfc  = (const float*)d_in[14];
    float* out = (float*)d_out;
    unsigned short* hbuf = (unsigned short*)d_ws;   // [256][2048][128] bf16 = 134 MB

    dim3 grid(BATCH / 16), block(512);
    lstm_layer<true,  true,  false><<<grid, block, 0, stream>>>(x,       Wih0, Whh0, bih0, bhh0, hbuf, nullptr, nullptr, nullptr);
    lstm_layer<false, true,  false><<<grid, block, 0, stream>>>(nullptr, Wih1, Whh1, bih1, bhh1, hbuf, nullptr, nullptr, nullptr);
    lstm_layer<false, false, true ><<<grid, block, 0, stream>>>(nullptr, Wih2, Whh2, bih2, bhh2, hbuf, Wfc,     bfc,     out);
}

// Round 3
// 847.144 us; speedup vs baseline: 1.6551x; 1.6408x over previous
//
#include <hip/hip_runtime.h>

#define T_STEPS 256
#define BATCH   2048
#define HID     128

typedef short short8  __attribute__((ext_vector_type(8)));
typedef short short4v __attribute__((ext_vector_type(4)));
typedef float float4v __attribute__((ext_vector_type(4)));

__device__ __forceinline__ unsigned short f2bf(float f) {
    unsigned int u = __builtin_bit_cast(unsigned int, f);
    u += 0x7fffu + ((u >> 16) & 1u);          // round-to-nearest-even
    return (unsigned short)(u >> 16);
}
__device__ __forceinline__ float bf2f(unsigned short b) {
    unsigned int u = ((unsigned int)b) << 16;
    return __builtin_bit_cast(float, u);
}

// Fast activations: raw v_exp_f32 (exp2) + v_rcp_f32. ~4-5 VALU instr each
// (vs 10-15 for the IEEE divide hipcc emits for 1.0f/x without fast-math).
#if __has_builtin(__builtin_amdgcn_exp2f)
#define EXP2F(x) __builtin_amdgcn_exp2f(x)
#else
#define EXP2F(x) exp2f(x)
#endif
__device__ __forceinline__ float sigf(float x) {
    // 1/(1+2^(-x*log2e))
    return __builtin_amdgcn_rcpf(1.0f + EXP2F(x * -1.442695041f));
}
__device__ __forceinline__ float tanh_fast(float x) {
    // 2/(1+2^(-2x*log2e)) - 1 ; saturates correctly at +-1
    return 2.0f * __builtin_amdgcn_rcpf(1.0f + EXP2F(x * -2.885390082f)) - 1.0f;
}

// Raw block barrier WITHOUT the vmcnt(0) drain __syncthreads() implies:
// LDS ops ordered (lgkmcnt(0) writer-side), global loads/stores stay in
// flight across steps (the compiler inserts counted vmcnt before any
// data-dependent use).
__device__ __forceinline__ void block_sync_lds() {
    asm volatile("s_waitcnt lgkmcnt(0)" ::: "memory");
    __builtin_amdgcn_s_barrier();
    __builtin_amdgcn_sched_barrier(0);
}

// LDS address within one 8 KB buffer: a[16 rows][512 B], XOR-swizzled (G4).
__device__ __forceinline__ int lpos(int row, int byteoff) {
    return (row * 512 + byteoff) ^ ((row & 7) << 4);
}

__device__ __forceinline__ short8 load_w8(const float* __restrict__ p) {
    float4v a = *reinterpret_cast<const float4v*>(p);
    float4v b = *reinterpret_cast<const float4v*>(p + 4);
    short8 r;
    r[0] = (short)f2bf(a[0]); r[1] = (short)f2bf(a[1]);
    r[2] = (short)f2bf(a[2]); r[3] = (short)f2bf(a[3]);
    r[4] = (short)f2bf(b[0]); r[5] = (short)f2bf(b[1]);
    r[6] = (short)f2bf(b[2]); r[7] = (short)f2bf(b[3]);
    return r;
}

// One LSTM layer. Block = 512 thr (8 waves), 16 batch rows, persistent over T.
// Ping-pong LDS (1 raw barrier/step), depth-2 x prefetch, weights in registers.
template<bool IS_L0, bool WRITE_H, bool FINAL>
__global__ __launch_bounds__(512, 2)
void lstm_layer(const float* __restrict__ x0,
                const float* __restrict__ Wih,
                const float* __restrict__ Whh,
                const float* __restrict__ bih,
                const float* __restrict__ bhh,
                unsigned short* __restrict__ hbuf,   // [T][B][H] bf16
                const float* __restrict__ Wfc,
                const float* __restrict__ bfc,
                float* __restrict__ out)
{
    constexpr int KS_TOT = IS_L0 ? 5 : 8;
    __shared__ __attribute__((aligned(16))) unsigned char a_lds[2 * 16 * 512];

    const int tid   = threadIdx.x;
    const int lane  = tid & 63;
    const int wv    = tid >> 6;
    const int b0    = blockIdx.x * 16;

    const int t16   = lane & 15;
    const int kgrp8 = (lane >> 4) * 8;
    const int jcol  = 16 * wv + t16;
    const int m0    = (lane >> 4) * 4;

    // precomputed LDS offsets (within one buffer; add rb/wb = 0 or 8192)
    int aoff[KS_TOT];
    #pragma unroll
    for (int ks = 0; ks < KS_TOT; ++ks) {
        const int boff = (ks < 4) ? (ks * 64 + kgrp8 * 2)
                                  : (256 + (ks - 4) * 64 + kgrp8 * 2);
        aoff[ks] = lpos(t16, boff);
    }
    int hwoff[4];
    #pragma unroll
    for (int r = 0; r < 4; ++r) hwoff[r] = lpos(m0 + r, 2 * jcol);

    // staging map: 512 threads x 8 B cover 16 rows x 256 B
    const int srow  = tid >> 5, so8 = tid & 31;
    const int hroff = lpos(srow, so8 * 8);            // h region read (for global write)
    const int sloff = lpos(srow, 256 + so8 * 8);      // x region write
    const size_t sgoff = (size_t)(b0 + srow) * HID + so8 * 4;  // shorts
    // L0 x staging: 384 threads x 1 float cover 16 rows x 24
    const int  xrow   = tid / 24, xe = tid % 24;
    const bool xvalid = tid < 384;
    const int  l0_loff = xvalid ? lpos(xrow, 256 + 2 * xe) : 0;
    const size_t l0_goff = xvalid ? ((size_t)(b0 + xrow) * (T_STEPS * 24) + xe) : 0;

    // ---- weights -> registers ----
    short8 wf[4][KS_TOT];
    float  bias[4];
    #pragma unroll
    for (int q = 0; q < 4; ++q) {
        const int n = 128 * q + jcol;
        bias[q] = bih[n] + bhh[n];
        #pragma unroll
        for (int ks = 0; ks < 4; ++ks)
            wf[q][ks] = load_w8(Whh + n * 128 + ks * 32 + kgrp8);
        if (IS_L0) {
            if (kgrp8 < 24) wf[q][4] = load_w8(Wih + n * 24 + kgrp8);
            else            { short8 z = {0,0,0,0,0,0,0,0}; wf[q][4] = z; }
        } else {
            #pragma unroll
            for (int ks = 4; ks < 8; ++ks)
                wf[q][ks] = load_w8(Wih + n * 128 + (ks - 4) * 32 + kgrp8);
        }
    }

    // zero both LDS buffers (h(-1)=0; pad columns stay 0)
    {
        short8 z = {0,0,0,0,0,0,0,0};
        *reinterpret_cast<short8*>(&a_lds[tid * 16])        = z;
        *reinterpret_cast<short8*>(&a_lds[8192 + tid * 16]) = z;
    }
    __syncthreads();

    // prologue: stage x(0) into buf0; hold x(1) in regs
    short4v xh = {0, 0, 0, 0};
    float   xf = 0.f;
    if (!IS_L0) {
        short4v v0 = *reinterpret_cast<const short4v*>(&hbuf[sgoff]);  // t=0
        *reinterpret_cast<short4v*>(&a_lds[sloff]) = v0;
        xh = *reinterpret_cast<const short4v*>(&hbuf[(size_t)BATCH * HID + sgoff]); // t=1
    } else if (xvalid) {
        float v0 = x0[l0_goff];
        *reinterpret_cast<unsigned short*>(&a_lds[l0_loff]) = f2bf(v0);
        xf = x0[l0_goff + 24];                                          // t=1
    }
    __syncthreads();

    float creg[4] = {0.f, 0.f, 0.f, 0.f};

    auto step = [&](int t, int rb, int wb) {
        // A: global write of h(t-1) (in read buffer), overlapped with compute
        if (WRITE_H && t > 0) {
            short4v hv = *reinterpret_cast<const short4v*>(&a_lds[rb + hroff]);
            *reinterpret_cast<short4v*>(
                &hbuf[(size_t)(t - 1) * (BATCH * HID) + sgoff]) = hv;
        }
        // B: stage x(t+1) from regs loaded a full step ago
        if (t + 1 < T_STEPS) {
            if (!IS_L0)
                *reinterpret_cast<short4v*>(&a_lds[wb + sloff]) = xh;
            else if (xvalid)
                *reinterpret_cast<unsigned short*>(&a_lds[wb + l0_loff]) = f2bf(xf);
        }
        // C: issue load of x(t+2)
        if (t + 2 < T_STEPS) {
            if (!IS_L0)
                xh = *reinterpret_cast<const short4v*>(
                    &hbuf[(size_t)(t + 2) * (BATCH * HID) + sgoff]);
            else if (xvalid)
                xf = x0[l0_goff + (size_t)(t + 2) * 24];
        }
        // D: MFMA, split even/odd-ks chains (8 independent chains)
        float4v aA[4], aB[4];
        #pragma unroll
        for (int q = 0; q < 4; ++q) {
            aA[q] = float4v{bias[q], bias[q], bias[q], bias[q]};
            aB[q] = float4v{0.f, 0.f, 0.f, 0.f};
        }
        #pragma unroll
        for (int ks = 0; ks < KS_TOT; ++ks) {
            short8 av = *reinterpret_cast<const short8*>(&a_lds[rb + aoff[ks]]);
            if (ks & 1) {
                #pragma unroll
                for (int q = 0; q < 4; ++q)
                    aB[q] = __builtin_amdgcn_mfma_f32_16x16x32_bf16(av, wf[q][ks], aB[q], 0, 0, 0);
            } else {
                #pragma unroll
                for (int q = 0; q < 4; ++q)
                    aA[q] = __builtin_amdgcn_mfma_f32_16x16x32_bf16(av, wf[q][ks], aA[q], 0, 0, 0);
            }
        }
        // E/F: lane-local cell update, write h(t) into write buffer
        #pragma unroll
        for (int r = 0; r < 4; ++r) {
            const float iv = sigf(aA[0][r] + aB[0][r]);
            const float fv = sigf(aA[1][r] + aB[1][r]);
            const float gv = tanh_fast(aA[2][r] + aB[2][r]);
            const float ov = sigf(aA[3][r] + aB[3][r]);
            const float cv = fv * creg[r] + iv * gv;
            creg[r] = cv;
            *reinterpret_cast<unsigned short*>(&a_lds[wb + hwoff[r]]) =
                f2bf(ov * tanh_fast(cv));
        }
        // G: single raw barrier per step (no vmcnt drain)
        block_sync_lds();
    };

    for (int th = 0; th < T_STEPS / 2; ++th) {
        step(2 * th,     0,    8192);
        step(2 * th + 1, 8192, 0);
    }
    // h(T-1) sits in buf0; last raw barrier already executed.
    if (WRITE_H) {
        short4v hv = *reinterpret_cast<const short4v*>(&a_lds[hroff]);
        *reinterpret_cast<short4v*>(
            &hbuf[(size_t)(T_STEPS - 1) * (BATCH * HID) + sgoff]) = hv;
    }
    // fused final FC (wave-parallel): out[b] = h_255[b] . Wfc + bfc
    if (FINAL && tid < 256) {
        const int r = tid >> 4, seg = tid & 15;
        float s = 0.f;
        #pragma unroll
        for (int k = 0; k < 8; ++k) {
            const int j = seg * 8 + k;
            s += bf2f(*reinterpret_cast<const unsigned short*>(&a_lds[lpos(r, 2 * j)]))
                 * Wfc[j];
        }
        #pragma unroll
        for (int off = 8; off >= 1; off >>= 1) s += __shfl_xor(s, off);
        if (seg == 0) out[b0 + r] = s + bfc[0];
    }
}

extern "C" void kernel_launch(void* const* d_in, const int* in_sizes, int n_in,
                              void* d_out, int out_size, void* d_ws, size_t ws_size,
                              hipStream_t stream) {
    (void)in_sizes; (void)n_in; (void)out_size; (void)ws_size;
    const float* x    = (const float*)d_in[0];
    const float* Wih0 = (const float*)d_in[1];
    const float* Whh0 = (const float*)d_in[2];
    const float* bih0 = (const float*)d_in[3];
    const float* bhh0 = (const float*)d_in[4];
    const float* Wih1 = (const float*)d_in[5];
    const float* Whh1 = (const float*)d_in[6];
    const float* bih1 = (const float*)d_in[7];
    const float* bhh1 = (const float*)d_in[8];
    const float* Wih2 = (const float*)d_in[9];
    const float* Whh2 = (const float*)d_in[10];
    const float* bih2 = (const float*)d_in[11];
    const float* bhh2 = (const float*)d_in[12];
    const float* Wfc  = (const float*)d_in[13];
    const float* bfc  = (const float*)d_in[14];
    float* out = (float*)d_out;
    unsigned short* hbuf = (unsigned short*)d_ws;   // [256][2048][128] bf16 = 134 MB

    dim3 grid(BATCH / 16), block(512);
    lstm_layer<true,  true,  false><<<grid, block, 0, stream>>>(x,       Wih0, Whh0, bih0, bhh0, hbuf, nullptr, nullptr, nullptr);
    lstm_layer<false, true,  false><<<grid, block, 0, stream>>>(nullptr, Wih1, Whh1, bih1, bhh1, hbuf, nullptr, nullptr, nullptr);
    lstm_layer<false, false, true ><<<grid, block, 0, stream>>>(nullptr, Wih2, Whh2, bih2, bhh2, hbuf, Wfc,     bfc,     out);
}

// Round 4
// 756.111 us; speedup vs baseline: 1.8544x; 1.1204x over previous
//
#include <hip/hip_runtime.h>

#define T_STEPS 256
#define BATCH   2048
#define HID     128
#define ROWS    8          // batch rows per block (grid = BATCH/ROWS = 256)

typedef short short8  __attribute__((ext_vector_type(8)));
typedef short short4v __attribute__((ext_vector_type(4)));
typedef float float4v __attribute__((ext_vector_type(4)));

__device__ __forceinline__ unsigned short f2bf(float f) {
    unsigned int u = __builtin_bit_cast(unsigned int, f);
    u += 0x7fffu + ((u >> 16) & 1u);
    return (unsigned short)(u >> 16);
}
__device__ __forceinline__ float bf2f(unsigned short b) {
    unsigned int u = ((unsigned int)b) << 16;
    return __builtin_bit_cast(float, u);
}

#if __has_builtin(__builtin_amdgcn_exp2f)
#define EXP2F(x) __builtin_amdgcn_exp2f(x)
#else
#define EXP2F(x) exp2f(x)
#endif
__device__ __forceinline__ float sigf(float x) {
    return __builtin_amdgcn_rcpf(1.0f + EXP2F(x * -1.442695041f));
}
__device__ __forceinline__ float tanh_fast(float x) {
    return 2.0f * __builtin_amdgcn_rcpf(1.0f + EXP2F(x * -2.885390082f)) - 1.0f;
}

// Raw barrier without the vmcnt(0) drain of __syncthreads().
__device__ __forceinline__ void block_sync_lds() {
    asm volatile("s_waitcnt lgkmcnt(0)" ::: "memory");
    __builtin_amdgcn_s_barrier();
    __builtin_amdgcn_sched_barrier(0);
}

// LDS addr in one 4 KB buffer: a[8 rows][512 B], XOR-swizzled (G4).
__device__ __forceinline__ int lpos(int row, int byteoff) {
    return (row * 512 + byteoff) ^ ((row & 7) << 4);
}

__device__ __forceinline__ short8 load_w8(const float* __restrict__ p) {
    float4v a = *reinterpret_cast<const float4v*>(p);
    float4v b = *reinterpret_cast<const float4v*>(p + 4);
    short8 r;
    r[0] = (short)f2bf(a[0]); r[1] = (short)f2bf(a[1]);
    r[2] = (short)f2bf(a[2]); r[3] = (short)f2bf(a[3]);
    r[4] = (short)f2bf(b[0]); r[5] = (short)f2bf(b[1]);
    r[6] = (short)f2bf(b[2]); r[7] = (short)f2bf(b[3]);
    return r;
}

// One LSTM layer. Block = 512 thr (8 waves), 8 batch rows, grid 256 (all CUs).
// A-tile rows 8-15 aliased to 0-7 (LDS broadcast): MFMA acc rows 8-15 become
// duplicates, so upper lanes consume acc regs {2,3} = rows 2,3/6,7 -> exactly
// 2 cell updates per thread, no cross-lane traffic.
template<bool IS_L0, bool WRITE_H, bool FINAL>
__global__ __launch_bounds__(512, 2)
void lstm_layer(const float* __restrict__ x0,
                const float* __restrict__ Wih,
                const float* __restrict__ Whh,
                const float* __restrict__ bih,
                const float* __restrict__ bhh,
                unsigned short* __restrict__ hbuf,   // [T][B][H] bf16
                const float* __restrict__ Wfc,
                const float* __restrict__ bfc,
                float* __restrict__ out)
{
    constexpr int KS_TOT = IS_L0 ? 5 : 8;
    constexpr int BUF = ROWS * 512;                  // 4096 B per buffer
    __shared__ __attribute__((aligned(16))) unsigned char a_lds[2 * BUF];

    const int tid   = threadIdx.x;
    const int lane  = tid & 63;
    const int wv    = tid >> 6;
    const int b0    = blockIdx.x * ROWS;

    const int t16   = lane & 15;
    const int kgrp8 = (lane >> 4) * 8;
    const int jcol  = 16 * wv + t16;                 // owned gate/h column
    const int m0    = (lane >> 4) * 4;
    const bool upper = (lane >= 32);                 // consumes acc regs {2,3}
    const int rbase  = upper ? 2 : 0;
    const int row0   = (m0 & 7) + rbase;             // this thread's 2 rows: row0, row0+1

    // A-fragment offsets: row aliased to &7 (broadcast pairs)
    int aoff[KS_TOT];
    #pragma unroll
    for (int ks = 0; ks < KS_TOT; ++ks) {
        const int boff = (ks < 4) ? (ks * 64 + kgrp8 * 2)
                                  : (256 + (ks - 4) * 64 + kgrp8 * 2);
        aoff[ks] = lpos(t16 & 7, boff);
    }
    const int hwoff0 = lpos(row0,     2 * jcol);
    const int hwoff1 = lpos(row0 + 1, 2 * jcol);

    // staging map (tid<256): 8 B/thread covers 8 rows x 256 B
    const int srow  = tid >> 5, so8 = tid & 31;
    const int hroff = lpos(srow, so8 * 8);
    const int sloff = lpos(srow, 256 + so8 * 8);
    const size_t sgoff = (size_t)(b0 + srow) * HID + so8 * 4;   // shorts
    // L0 x staging: 192 threads x 1 float cover 8 rows x 24
    const int  xrow   = tid / 24, xe = tid % 24;
    const bool xvalid = tid < 192;
    const int  l0_loff = xvalid ? lpos(xrow, 256 + 2 * xe) : 0;
    const size_t l0_goff = xvalid ? ((size_t)(b0 + xrow) * (T_STEPS * 24) + xe) : 0;

    // ---- weights -> registers ----
    short8 wf[4][KS_TOT];
    float  bias[4];
    #pragma unroll
    for (int q = 0; q < 4; ++q) {
        const int n = 128 * q + jcol;
        bias[q] = bih[n] + bhh[n];
        #pragma unroll
        for (int ks = 0; ks < 4; ++ks)
            wf[q][ks] = load_w8(Whh + n * 128 + ks * 32 + kgrp8);
        if (IS_L0) {
            if (kgrp8 < 24) wf[q][4] = load_w8(Wih + n * 24 + kgrp8);
            else            { short8 z = {0,0,0,0,0,0,0,0}; wf[q][4] = z; }
        } else {
            #pragma unroll
            for (int ks = 4; ks < 8; ++ks)
                wf[q][ks] = load_w8(Wih + n * 128 + (ks - 4) * 32 + kgrp8);
        }
    }

    // zero both buffers (h(-1)=0; pads stay 0): 512 thr x 16 B = 8 KB
    {
        short8 z = {0,0,0,0,0,0,0,0};
        *reinterpret_cast<short8*>(&a_lds[tid * 16]) = z;
    }
    __syncthreads();

    // prologue: stage x(0) into buf0; hold x(1) in regs
    short4v xh = {0, 0, 0, 0};
    float   xf = 0.f;
    if (!IS_L0) {
        if (tid < 256) {
            short4v v0 = *reinterpret_cast<const short4v*>(&hbuf[sgoff]);
            *reinterpret_cast<short4v*>(&a_lds[sloff]) = v0;
            xh = *reinterpret_cast<const short4v*>(&hbuf[(size_t)BATCH * HID + sgoff]);
        }
    } else if (xvalid) {
        float v0 = x0[l0_goff];
        *reinterpret_cast<unsigned short*>(&a_lds[l0_loff]) = f2bf(v0);
        xf = x0[l0_goff + 24];
    }
    __syncthreads();

    float creg[2] = {0.f, 0.f};

    auto step = [&](int t, int rb, int wb) {
        // A: global write of h(t-1) from read buffer (overlaps compute)
        if (WRITE_H && t > 0 && tid < 256) {
            short4v hv = *reinterpret_cast<const short4v*>(&a_lds[rb + hroff]);
            *reinterpret_cast<short4v*>(
                &hbuf[(size_t)(t - 1) * (BATCH * HID) + sgoff]) = hv;
        }
        // B: stage x(t+1) from regs loaded a full step ago
        if (t + 1 < T_STEPS) {
            if (!IS_L0) {
                if (tid < 256)
                    *reinterpret_cast<short4v*>(&a_lds[wb + sloff]) = xh;
            } else if (xvalid)
                *reinterpret_cast<unsigned short*>(&a_lds[wb + l0_loff]) = f2bf(xf);
        }
        // C: issue load of x(t+2)
        if (t + 2 < T_STEPS) {
            if (!IS_L0) {
                if (tid < 256)
                    xh = *reinterpret_cast<const short4v*>(
                        &hbuf[(size_t)(t + 2) * (BATCH * HID) + sgoff]);
            } else if (xvalid)
                xf = x0[l0_goff + (size_t)(t + 2) * 24];
        }
        // D: MFMA, even/odd-ks chains
        float4v aA[4], aB[4];
        #pragma unroll
        for (int q = 0; q < 4; ++q) {
            aA[q] = float4v{bias[q], bias[q], bias[q], bias[q]};
            aB[q] = float4v{0.f, 0.f, 0.f, 0.f};
        }
        #pragma unroll
        for (int ks = 0; ks < KS_TOT; ++ks) {
            short8 av = *reinterpret_cast<const short8*>(&a_lds[rb + aoff[ks]]);
            if (ks & 1) {
                #pragma unroll
                for (int q = 0; q < 4; ++q)
                    aB[q] = __builtin_amdgcn_mfma_f32_16x16x32_bf16(av, wf[q][ks], aB[q], 0, 0, 0);
            } else {
                #pragma unroll
                for (int q = 0; q < 4; ++q)
                    aA[q] = __builtin_amdgcn_mfma_f32_16x16x32_bf16(av, wf[q][ks], aA[q], 0, 0, 0);
            }
        }
        // E: 2 cell updates/thread (regs rbase, rbase+1)
        float g0[4], g1[4];
        #pragma unroll
        for (int q = 0; q < 4; ++q) {
            g0[q] = upper ? (aA[q][2] + aB[q][2]) : (aA[q][0] + aB[q][0]);
            g1[q] = upper ? (aA[q][3] + aB[q][3]) : (aA[q][1] + aB[q][1]);
        }
        const float c0 = sigf(g0[1]) * creg[0] + sigf(g0[0]) * tanh_fast(g0[2]);
        const float c1 = sigf(g1[1]) * creg[1] + sigf(g1[0]) * tanh_fast(g1[2]);
        creg[0] = c0;  creg[1] = c1;
        const float h0 = sigf(g0[3]) * tanh_fast(c0);
        const float h1 = sigf(g1[3]) * tanh_fast(c1);
        unsigned int packed;
        asm("v_cvt_pk_bf16_f32 %0, %1, %2" : "=v"(packed) : "v"(h0), "v"(h1));
        *reinterpret_cast<unsigned short*>(&a_lds[wb + hwoff0]) =
            (unsigned short)(packed & 0xffffu);
        *reinterpret_cast<unsigned short*>(&a_lds[wb + hwoff1]) =
            (unsigned short)(packed >> 16);
        // F: single raw barrier per step
        block_sync_lds();
    };

    for (int th = 0; th < T_STEPS / 2; ++th) {
        step(2 * th,     0,   BUF);
        step(2 * th + 1, BUF, 0);
    }
    // h(T-1) is in buffer 0
    if (WRITE_H && tid < 256) {
        short4v hv = *reinterpret_cast<const short4v*>(&a_lds[hroff]);
        *reinterpret_cast<short4v*>(
            &hbuf[(size_t)(T_STEPS - 1) * (BATCH * HID) + sgoff]) = hv;
    }
    // fused final FC: out[b] = h_255[b] . Wfc + bfc
    if (FINAL && tid < 128) {
        const int r = tid >> 4, seg = tid & 15;
        float s = 0.f;
        #pragma unroll
        for (int k = 0; k < 8; ++k) {
            const int j = seg * 8 + k;
            s += bf2f(*reinterpret_cast<const unsigned short*>(&a_lds[lpos(r, 2 * j)]))
                 * Wfc[j];
        }
        #pragma unroll
        for (int off = 8; off >= 1; off >>= 1) s += __shfl_xor(s, off);
        if (seg == 0) out[b0 + r] = s + bfc[0];
    }
}

extern "C" void kernel_launch(void* const* d_in, const int* in_sizes, int n_in,
                              void* d_out, int out_size, void* d_ws, size_t ws_size,
                              hipStream_t stream) {
    (void)in_sizes; (void)n_in; (void)out_size; (void)ws_size;
    const float* x    = (const float*)d_in[0];
    const float* Wih0 = (const float*)d_in[1];
    const float* Whh0 = (const float*)d_in[2];
    const float* bih0 = (const float*)d_in[3];
    const float* bhh0 = (const float*)d_in[4];
    const float* Wih1 = (const float*)d_in[5];
    const float* Whh1 = (const float*)d_in[6];
    const float* bih1 = (const float*)d_in[7];
    const float* bhh1 = (const float*)d_in[8];
    const float* Wih2 = (const float*)d_in[9];
    const float* Whh2 = (const float*)d_in[10];
    const float* bih2 = (const float*)d_in[11];
    const float* bhh2 = (const float*)d_in[12];
    const float* Wfc  = (const float*)d_in[13];
    const float* bfc  = (const float*)d_in[14];
    float* out = (float*)d_out;
    unsigned short* hbuf = (unsigned short*)d_ws;   // [256][2048][128] bf16 = 134 MB

    dim3 grid(BATCH / ROWS), block(512);
    lstm_layer<true,  true,  false><<<grid, block, 0, stream>>>(x,       Wih0, Whh0, bih0, bhh0, hbuf, nullptr, nullptr, nullptr);
    lstm_layer<false, true,  false><<<grid, block, 0, stream>>>(nullptr, Wih1, Whh1, bih1, bhh1, hbuf, nullptr, nullptr, nullptr);
    lstm_layer<false, false, true ><<<grid, block, 0, stream>>>(nullptr, Wih2, Whh2, bih2, bhh2, hbuf, Wfc,     bfc,     out);
}

// Round 5
// 660.714 us; speedup vs baseline: 2.1221x; 1.1444x over previous
//
#include <hip/hip_runtime.h>

#define T_STEPS 256
#define BATCH   2048
#define HID     128
#define ROWS    8          // batch rows per block (grid = BATCH/ROWS = 256)

typedef short short8  __attribute__((ext_vector_type(8)));
typedef float float4v __attribute__((ext_vector_type(4)));

__device__ __forceinline__ unsigned short f2bf(float f) {
    unsigned int u = __builtin_bit_cast(unsigned int, f);
    u += 0x7fffu + ((u >> 16) & 1u);
    return (unsigned short)(u >> 16);
}
__device__ __forceinline__ float bf2f(unsigned short b) {
    unsigned int u = ((unsigned int)b) << 16;
    return __builtin_bit_cast(float, u);
}

#if __has_builtin(__builtin_amdgcn_exp2f)
#define EXP2F(x) __builtin_amdgcn_exp2f(x)
#else
#define EXP2F(x) exp2f(x)
#endif
__device__ __forceinline__ float sigf(float x) {
    return __builtin_amdgcn_rcpf(1.0f + EXP2F(x * -1.442695041f));
}
__device__ __forceinline__ float tanh_fast(float x) {
    return 2.0f * __builtin_amdgcn_rcpf(1.0f + EXP2F(x * -2.885390082f)) - 1.0f;
}

// Raw barrier without the vmcnt(0) drain of __syncthreads().
__device__ __forceinline__ void block_sync_lds() {
    asm volatile("s_waitcnt lgkmcnt(0)" ::: "memory");
    __builtin_amdgcn_s_barrier();
    __builtin_amdgcn_sched_barrier(0);
}

// LDS addr in one 4 KB buffer: a[8 rows][512 B], XOR-swizzled (G4).
__device__ __forceinline__ int lpos(int row, int byteoff) {
    return (row * 512 + byteoff) ^ ((row & 7) << 4);
}

__device__ __forceinline__ short8 load_w8(const float* __restrict__ p) {
    float4v a = *reinterpret_cast<const float4v*>(p);
    float4v b = *reinterpret_cast<const float4v*>(p + 4);
    short8 r;
    r[0] = (short)f2bf(a[0]); r[1] = (short)f2bf(a[1]);
    r[2] = (short)f2bf(a[2]); r[3] = (short)f2bf(a[3]);
    r[4] = (short)f2bf(b[0]); r[5] = (short)f2bf(b[1]);
    r[6] = (short)f2bf(b[2]); r[7] = (short)f2bf(b[3]);
    return r;
}

// One LSTM layer. Block = 512 thr (8 waves), 8 batch rows, grid 256 (all CUs).
// A-tile rows 8-15 aliased to 0-7 (LDS broadcast); upper lanes consume acc
// regs {2,3}, lower {0,1} -> 2 cell updates/thread, lane-local.
// Weights live in registers/AGPRs (unified file) -> ~256 regs/wave -> 8
// waves/CU residency ceiling (1 block/CU). Single bias-initialized MFMA
// chain per gate; staging spread over all 512 threads.
template<bool IS_L0, bool WRITE_H, bool FINAL>
__global__ __launch_bounds__(512, 2)
void lstm_layer(const float* __restrict__ x0,
                const float* __restrict__ Wih,
                const float* __restrict__ Whh,
                const float* __restrict__ bih,
                const float* __restrict__ bhh,
                unsigned short* __restrict__ hbuf,   // [T][B][H] bf16
                const float* __restrict__ Wfc,
                const float* __restrict__ bfc,
                float* __restrict__ out)
{
    constexpr int KS_TOT = IS_L0 ? 5 : 8;
    constexpr int BUF = ROWS * 512;                  // 4096 B per buffer
    __shared__ __attribute__((aligned(16))) unsigned char a_lds[2 * BUF];

    const int tid   = threadIdx.x;
    const int lane  = tid & 63;
    const int wv    = tid >> 6;
    const int b0    = blockIdx.x * ROWS;

    const int t16   = lane & 15;
    const int kgrp8 = (lane >> 4) * 8;
    const int jcol  = 16 * wv + t16;                 // owned gate/h column
    const int m0    = (lane >> 4) * 4;
    const bool upper = (lane >= 32);                 // consumes acc regs {2,3}
    const int rbase  = upper ? 2 : 0;
    const int row0   = (m0 & 7) + rbase;             // this thread's 2 rows

    // A-fragment offsets: row aliased to &7 (broadcast pairs)
    int aoff[KS_TOT];
    #pragma unroll
    for (int ks = 0; ks < KS_TOT; ++ks) {
        const int boff = (ks < 4) ? (ks * 64 + kgrp8 * 2)
                                  : (256 + (ks - 4) * 64 + kgrp8 * 2);
        aoff[ks] = lpos(t16 & 7, boff);
    }
    const int hwoff0 = lpos(row0,     2 * jcol);
    const int hwoff1 = lpos(row0 + 1, 2 * jcol);

    // staging map: ALL 512 threads x 4 B cover 8 rows x 256 B
    const int srow4 = tid >> 6, scol4 = tid & 63;           // row, dword idx
    const int hroff4 = lpos(srow4, scol4 * 4);              // h region (global write)
    const int sloff4 = lpos(srow4, 256 + scol4 * 4);        // x region (LDS write)
    const size_t sgoff4 = (size_t)(b0 + srow4) * HID + scol4 * 2;  // shorts
    // L0 x staging: 192 threads x 1 float cover 8 rows x 24
    const int  xrow   = tid / 24, xe = tid % 24;
    const bool xvalid = tid < 192;
    const int  l0_loff = xvalid ? lpos(xrow, 256 + 2 * xe) : 0;
    const size_t l0_goff = xvalid ? ((size_t)(b0 + xrow) * (T_STEPS * 24) + xe) : 0;

    // ---- weights -> registers ----
    short8 wf[4][KS_TOT];
    float  bias[4];
    #pragma unroll
    for (int q = 0; q < 4; ++q) {
        const int n = 128 * q + jcol;
        bias[q] = bih[n] + bhh[n];
        #pragma unroll
        for (int ks = 0; ks < 4; ++ks)
            wf[q][ks] = load_w8(Whh + n * 128 + ks * 32 + kgrp8);
        if (IS_L0) {
            if (kgrp8 < 24) wf[q][4] = load_w8(Wih + n * 24 + kgrp8);
            else            { short8 z = {0,0,0,0,0,0,0,0}; wf[q][4] = z; }
        } else {
            #pragma unroll
            for (int ks = 4; ks < 8; ++ks)
                wf[q][ks] = load_w8(Wih + n * 128 + (ks - 4) * 32 + kgrp8);
        }
    }

    // zero both buffers (h(-1)=0; pads stay 0): 512 thr x 16 B = 8 KB
    {
        short8 z = {0,0,0,0,0,0,0,0};
        *reinterpret_cast<short8*>(&a_lds[tid * 16]) = z;
    }
    __syncthreads();

    // prologue: stage x(0) into buf0; hold x(1) in regs
    unsigned int xh = 0;
    float xf = 0.f;
    if (!IS_L0) {
        unsigned int v0 = *reinterpret_cast<const unsigned int*>(&hbuf[sgoff4]);
        *reinterpret_cast<unsigned int*>(&a_lds[sloff4]) = v0;
        xh = *reinterpret_cast<const unsigned int*>(&hbuf[(size_t)BATCH * HID + sgoff4]);
    } else if (xvalid) {
        float v0 = x0[l0_goff];
        *reinterpret_cast<unsigned short*>(&a_lds[l0_loff]) = f2bf(v0);
        xf = x0[l0_goff + 24];
    }
    __syncthreads();

    float creg[2] = {0.f, 0.f};

    auto step = [&](int t, int rb, int wb) {
        // A: global write of h(t-1) from read buffer (overlaps compute)
        if (WRITE_H && t > 0) {
            unsigned int hv = *reinterpret_cast<const unsigned int*>(&a_lds[rb + hroff4]);
            *reinterpret_cast<unsigned int*>(
                &hbuf[(size_t)(t - 1) * (BATCH * HID) + sgoff4]) = hv;
        }
        // B: stage x(t+1) from regs loaded a full step ago
        if (t + 1 < T_STEPS) {
            if (!IS_L0)
                *reinterpret_cast<unsigned int*>(&a_lds[wb + sloff4]) = xh;
            else if (xvalid)
                *reinterpret_cast<unsigned short*>(&a_lds[wb + l0_loff]) = f2bf(xf);
        }
        // C: issue load of x(t+2)
        if (t + 2 < T_STEPS) {
            if (!IS_L0)
                xh = *reinterpret_cast<const unsigned int*>(
                    &hbuf[(size_t)(t + 2) * (BATCH * HID) + sgoff4]);
            else if (xvalid)
                xf = x0[l0_goff + (size_t)(t + 2) * 24];
        }
        // D: MFMA, single bias-initialized chain per gate (4 interleaved chains)
        float4v acc[4];
        #pragma unroll
        for (int q = 0; q < 4; ++q)
            acc[q] = float4v{bias[q], bias[q], bias[q], bias[q]};
        __builtin_amdgcn_s_setprio(1);
        #pragma unroll
        for (int ks = 0; ks < KS_TOT; ++ks) {
            short8 av = *reinterpret_cast<const short8*>(&a_lds[rb + aoff[ks]]);
            #pragma unroll
            for (int q = 0; q < 4; ++q)
                acc[q] = __builtin_amdgcn_mfma_f32_16x16x32_bf16(av, wf[q][ks], acc[q], 0, 0, 0);
        }
        __builtin_amdgcn_s_setprio(0);
        // E: 2 cell updates/thread (regs rbase, rbase+1)
        float g0[4], g1[4];
        #pragma unroll
        for (int q = 0; q < 4; ++q) {
            g0[q] = upper ? acc[q][2] : acc[q][0];
            g1[q] = upper ? acc[q][3] : acc[q][1];
        }
        const float c0 = sigf(g0[1]) * creg[0] + sigf(g0[0]) * tanh_fast(g0[2]);
        const float c1 = sigf(g1[1]) * creg[1] + sigf(g1[0]) * tanh_fast(g1[2]);
        creg[0] = c0;  creg[1] = c1;
        const float h0 = sigf(g0[3]) * tanh_fast(c0);
        const float h1 = sigf(g1[3]) * tanh_fast(c1);
        unsigned int packed;
        asm("v_cvt_pk_bf16_f32 %0, %1, %2" : "=v"(packed) : "v"(h0), "v"(h1));
        *reinterpret_cast<unsigned short*>(&a_lds[wb + hwoff0]) =
            (unsigned short)(packed & 0xffffu);
        *reinterpret_cast<unsigned short*>(&a_lds[wb + hwoff1]) =
            (unsigned short)(packed >> 16);
        // F: single raw barrier per step
        block_sync_lds();
    };

    for (int th = 0; th < T_STEPS / 2; ++th) {
        step(2 * th,     0,   BUF);
        step(2 * th + 1, BUF, 0);
    }
    // h(T-1) is in buffer 0
    if (WRITE_H) {
        unsigned int hv = *reinterpret_cast<const unsigned int*>(&a_lds[hroff4]);
        *reinterpret_cast<unsigned int*>(
            &hbuf[(size_t)(T_STEPS - 1) * (BATCH * HID) + sgoff4]) = hv;
    }
    // fused final FC: out[b] = h_255[b] . Wfc + bfc
    if (FINAL && tid < 128) {
        const int r = tid >> 4, seg = tid & 15;
        float s = 0.f;
        #pragma unroll
        for (int k = 0; k < 8; ++k) {
            const int j = seg * 8 + k;
            s += bf2f(*reinterpret_cast<const unsigned short*>(&a_lds[lpos(r, 2 * j)]))
                 * Wfc[j];
        }
        #pragma unroll
        for (int off = 8; off >= 1; off >>= 1) s += __shfl_xor(s, off);
        if (seg == 0) out[b0 + r] = s + bfc[0];
    }
}

extern "C" void kernel_launch(void* const* d_in, const int* in_sizes, int n_in,
                              void* d_out, int out_size, void* d_ws, size_t ws_size,
                              hipStream_t stream) {
    (void)in_sizes; (void)n_in; (void)out_size; (void)ws_size;
    const float* x    = (const float*)d_in[0];
    const float* Wih0 = (const float*)d_in[1];
    const float* Whh0 = (const float*)d_in[2];
    const float* bih0 = (const float*)d_in[3];
    const float* bhh0 = (const float*)d_in[4];
    const float* Wih1 = (const float*)d_in[5];
    const float* Whh1 = (const float*)d_in[6];
    const float* bih1 = (const float*)d_in[7];
    const float* bhh1 = (const float*)d_in[8];
    const float* Wih2 = (const float*)d_in[9];
    const float* Whh2 = (const float*)d_in[10];
    const float* bih2 = (const float*)d_in[11];
    const float* bhh2 = (const float*)d_in[12];
    const float* Wfc  = (const float*)d_in[13];
    const float* bfc  = (const float*)d_in[14];
    float* out = (float*)d_out;
    unsigned short* hbuf = (unsigned short*)d_ws;   // [256][2048][128] bf16 = 134 MB

    dim3 grid(BATCH / ROWS), block(512);
    lstm_layer<true,  true,  false><<<grid, block, 0, stream>>>(x,       Wih0, Whh0, bih0, bhh0, hbuf, nullptr, nullptr, nullptr);
    lstm_layer<false, true,  false><<<grid, block, 0, stream>>>(nullptr, Wih1, Whh1, bih1, bhh1, hbuf, nullptr, nullptr, nullptr);
    lstm_layer<false, false, true ><<<grid, block, 0, stream>>>(nullptr, Wih2, Whh2, bih2, bhh2, hbuf, Wfc,     bfc,     out);
}